// Round 4
// baseline (5835.069 us; speedup 1.0000x reference)
//
#include <hip/hip_runtime.h>
#include <hip/hip_bf16.h>
#include <hip/hip_fp16.h>

#define B_ 128
#define S_ 128
#define I_ 300
#define H_ 1024
#define C_ 2

typedef __attribute__((ext_vector_type(8))) short short8;
typedef __attribute__((ext_vector_type(4))) float f32x4;

__device__ inline short f2b(float f) {
    union { __hip_bfloat16 h; unsigned short s; } cv;
    cv.h = __float2bfloat16(f);
    return (short)cv.s;
}

__global__ __launch_bounds__(256) void prep_bias(
    const float* __restrict__ b_ih, const float* __restrict__ b_hh,
    float* __restrict__ bias)
{
    int i = blockIdx.x * 256 + threadIdx.x;
    if (i < 4 * H_) bias[i] = b_ih[i] + b_hh[i];
}

// ---------------------------------------------------------------------------
// gates_ih[t*B+b][4096] = embed_W[x[b,t]] @ W_ih^T + (b_ih + b_hh), fp16.
// Embed gather fused into A staging. Tile 128x128, K=320 in 10 chunks of 32.
// grid (32 n-tiles, 128 t), 256 thr = 4 waves; wave w: rows w*32..w*32+31.
// ---------------------------------------------------------------------------
__global__ __launch_bounds__(256) void gemm_ih(
    const int* __restrict__ x,            // [B,S]
    const float* __restrict__ embed_W,    // [V,300]
    const float* __restrict__ W_ih,       // [4096,300]
    const float* __restrict__ bias,       // [4096]
    __half* __restrict__ gates)           // [S*B,4096]
{
    const int tid = threadIdx.x;
    const int wid = tid >> 6, lane = tid & 63;
    const int fr = lane & 15, fq = lane >> 4;
    const int bx = blockIdx.x;            // n-tile base bx*128
    const int t  = blockIdx.y;            // this m-tile is (t, all b)

    __shared__ alignas(16) unsigned short As_[128][40];
    __shared__ alignas(16) unsigned short Bs_[128][40];

    const int sr = tid >> 1;              // staging row 0..127
    const int sc = (tid & 1) * 16;        // staging col base (16 cols)
    const int token = x[sr * S_ + t];     // b = sr
    const float* arow = embed_W + (size_t)token * I_;
    const float* brow = W_ih + (size_t)(bx * 128 + sr) * I_;

    f32x4 acc[2][8] = {};

    for (int kc = 0; kc < 10; ++kc) {
        __syncthreads();
        const int k0 = kc * 32 + sc;
#pragma unroll
        for (int half = 0; half < 2; ++half) {
            const int kh = k0 + half * 8;
            short8 av, bv;
            if (kh + 7 < I_) {
                float4 alo = *(const float4*)(arow + kh);
                float4 ahi = *(const float4*)(arow + kh + 4);
                float4 blo = *(const float4*)(brow + kh);
                float4 bhi = *(const float4*)(brow + kh + 4);
                av[0]=f2b(alo.x); av[1]=f2b(alo.y); av[2]=f2b(alo.z); av[3]=f2b(alo.w);
                av[4]=f2b(ahi.x); av[5]=f2b(ahi.y); av[6]=f2b(ahi.z); av[7]=f2b(ahi.w);
                bv[0]=f2b(blo.x); bv[1]=f2b(blo.y); bv[2]=f2b(blo.z); bv[3]=f2b(blo.w);
                bv[4]=f2b(bhi.x); bv[5]=f2b(bhi.y); bv[6]=f2b(bhi.z); bv[7]=f2b(bhi.w);
            } else {
#pragma unroll
                for (int j = 0; j < 8; ++j) {
                    av[j] = (kh + j < I_) ? f2b(arow[kh + j]) : (short)0;
                    bv[j] = (kh + j < I_) ? f2b(brow[kh + j]) : (short)0;
                }
            }
            *(short8*)&As_[sr][sc + half * 8] = av;
            *(short8*)&Bs_[sr][sc + half * 8] = bv;
        }
        __syncthreads();
        short8 bfrag[8];
#pragma unroll
        for (int nt = 0; nt < 8; ++nt)
            bfrag[nt] = *(const short8*)&Bs_[nt * 16 + fr][fq * 8];
#pragma unroll
        for (int mt = 0; mt < 2; ++mt) {
            short8 a = *(const short8*)&As_[wid * 32 + mt * 16 + fr][fq * 8];
#pragma unroll
            for (int nt = 0; nt < 8; ++nt)
                acc[mt][nt] = __builtin_amdgcn_mfma_f32_16x16x32_bf16(
                    a, bfrag[nt], acc[mt][nt], 0, 0, 0);
        }
    }
    // epilogue: C row = fq*4+r (in-tile), col = fr
#pragma unroll
    for (int mt = 0; mt < 2; ++mt) {
        const int m = t * 128 + wid * 32 + mt * 16 + fq * 4;
#pragma unroll
        for (int nt = 0; nt < 8; ++nt) {
            const int n = bx * 128 + nt * 16 + fr;
            const float bs = bias[n];
#pragma unroll
            for (int r = 0; r < 4; ++r)
                gates[(size_t)(m + r) * 4096 + n] =
                    __float2half(acc[mt][nt][r] + bs);
        }
    }
}

// ---------------------------------------------------------------------------
// Persistent LSTM: 256 blocks (cooperative => co-resident), all 128 steps.
// Block (bg,ug): batches bg*32..+32, units ug*16..+16, all 4 gates.
// W_hh held in registers (32 b-frags/lane). c-state in registers.
// Barrier: 4 independent groups of 64 blocks (per batch-group), monotonic
// device-scope counter via atomicAdd + __threadfence (cross-XCD wbl2/inv).
// ---------------------------------------------------------------------------
__global__ __launch_bounds__(256, 1) void lstm_persist(
    const float* __restrict__ W_hh,       // [4096,1024] fp32
    const __half* __restrict__ gates_ih,  // [S*B,4096] incl bias
    __hip_bfloat16* __restrict__ hs,      // [S+1,B,H]
    int* __restrict__ bar)                // [4*64] counters (only [g*64] used)
{
    const int tid  = threadIdx.x;
    const int wid  = tid >> 6;            // wave = gate
    const int lane = tid & 63;
    const int ug = blockIdx.x & 63;
    const int bg = blockIdx.x >> 6;
    const int n0 = ug * 16;
    const int fr = lane & 15, fq = lane >> 4;
    const int m0g = bg * 32;              // batch base

    // row stride 520 shorts = 1040 B (16B-aligned rows; bank shift 4/row ->
    // 2-way max across the 16 rows an MFMA frag reads = free per m136).
    __shared__ alignas(16) unsigned short As[32][520];   // h_prev half-slab
    __shared__ float Gs[32][65];                          // gate exchange

    // ---- load W_hh fragments into registers (once) ----
    short8 bfr[32];
    {
        const float* wr =
            W_hh + ((size_t)(wid * H_ + n0 + fr)) * H_ + fq * 8;
#pragma unroll
        for (int f = 0; f < 32; ++f) {
            float4 lo = *(const float4*)(wr + f * 32);
            float4 hi = *(const float4*)(wr + f * 32 + 4);
            short8 b;
            b[0]=f2b(lo.x); b[1]=f2b(lo.y); b[2]=f2b(lo.z); b[3]=f2b(lo.w);
            b[4]=f2b(hi.x); b[5]=f2b(hi.y); b[6]=f2b(hi.z); b[7]=f2b(hi.w);
            bfr[f] = b;
        }
    }

    float c0 = 0.f, c1 = 0.f;             // c for e0=tid, e1=tid+256
    const int cm = tid >> 4, cu = tid & 15;
    int* cnt = bar + bg * 64;

    for (int t = 0; t < S_; ++t) {
        const __hip_bfloat16* hprev =
            hs + (size_t)t * (B_ * H_) + (size_t)m0g * H_;
        f32x4 acc0 = {0.f,0.f,0.f,0.f}, acc1 = {0.f,0.f,0.f,0.f};

#pragma unroll
        for (int half = 0; half < 2; ++half) {
            // stage As[32][512] = h_prev[:, half*512 .. +512]
#pragma unroll
            for (int i = 0; i < 8; ++i) {
                const int g = i * 256 + tid;       // 8-elem group id
                const int r = g >> 6;
                const int cc = (g & 63) * 8;
                *(short8*)&As[r][cc] =
                    *(const short8*)(hprev + r * H_ + half * 512 + cc);
            }
            __syncthreads();
            const unsigned short* a0p = &As[fr][fq * 8];
            const unsigned short* a1p = &As[16 + fr][fq * 8];
#pragma unroll
            for (int kf = 0; kf < 16; ++kf) {
                short8 a0 = *(const short8*)(a0p + kf * 32);
                short8 a1 = *(const short8*)(a1p + kf * 32);
                short8 bb = bfr[half * 16 + kf];
                acc0 = __builtin_amdgcn_mfma_f32_16x16x32_bf16(a0, bb, acc0, 0, 0, 0);
                acc1 = __builtin_amdgcn_mfma_f32_16x16x32_bf16(a1, bb, acc1, 0, 0, 0);
            }
            __syncthreads();                        // As reuse
        }

        // exchange gates: Gs[m][gate*16+u]
        {
            const int col = wid * 16 + fr;
            const int rb = fq * 4;
#pragma unroll
            for (int r = 0; r < 4; ++r) {
                Gs[rb + r][col]      = acc0[r];
                Gs[16 + rb + r][col] = acc1[r];
            }
        }
        __syncthreads();

        // cell update: e0=(cm,cu), e1=(cm+16,cu)
        {
            const size_t gb0 =
                ((size_t)t * B_ + m0g + cm) * 4096 + n0 + cu;
            const size_t gb1 = gb0 + (size_t)16 * 4096;
            float gi0 = Gs[cm][cu]      + __half2float(gates_ih[gb0]);
            float gf0 = Gs[cm][16 + cu] + __half2float(gates_ih[gb0 + 1024]);
            float gg0 = Gs[cm][32 + cu] + __half2float(gates_ih[gb0 + 2048]);
            float go0 = Gs[cm][48 + cu] + __half2float(gates_ih[gb0 + 3072]);
            float gi1 = Gs[cm+16][cu]      + __half2float(gates_ih[gb1]);
            float gf1 = Gs[cm+16][16 + cu] + __half2float(gates_ih[gb1 + 1024]);
            float gg1 = Gs[cm+16][32 + cu] + __half2float(gates_ih[gb1 + 2048]);
            float go1 = Gs[cm+16][48 + cu] + __half2float(gates_ih[gb1 + 3072]);
            float si0 = 1.f / (1.f + __expf(-gi0));
            float sf0 = 1.f / (1.f + __expf(-gf0));
            float so0 = 1.f / (1.f + __expf(-go0));
            float si1 = 1.f / (1.f + __expf(-gi1));
            float sf1 = 1.f / (1.f + __expf(-gf1));
            float so1 = 1.f / (1.f + __expf(-go1));
            c0 = sf0 * c0 + si0 * tanhf(gg0);
            c1 = sf1 * c1 + si1 * tanhf(gg1);
            float h0 = so0 * tanhf(c0);
            float h1 = so1 * tanhf(c1);
            __hip_bfloat16* hnext =
                hs + (size_t)(t + 1) * (B_ * H_);
            hnext[(size_t)(m0g + cm) * H_ + n0 + cu] = __float2bfloat16(h0);
            hnext[(size_t)(m0g + cm + 16) * H_ + n0 + cu] = __float2bfloat16(h1);
        }

        // inter-block barrier within batch-group (skip after last step)
        if (t < S_ - 1) {
            __threadfence();              // release: h stores -> agent scope
            __syncthreads();
            if (tid == 0) {
                atomicAdd(cnt, 1);
                const int target = 64 * (t + 1);
                while (atomicAdd(cnt, 0) < target)
                    __builtin_amdgcn_s_sleep(1);
            }
            __syncthreads();
            __threadfence();              // acquire: invalidate stale lines
        }
    }
}

// ---------------------------------------------------------------------------
// Head: one wave per (b,t): out = h . lin_W^T + lin_b, masked by lengths.
// ---------------------------------------------------------------------------
__global__ __launch_bounds__(256) void final_linear(
    const __hip_bfloat16* __restrict__ hs,   // [S+1,B,H]
    const float* __restrict__ lin_W,         // [2,H]
    const float* __restrict__ lin_b,         // [2]
    const int* __restrict__ lengths,         // [B]
    float* __restrict__ out)                 // [B*S,2]
{
    const int wid  = threadIdx.x >> 6;
    const int lane = threadIdx.x & 63;
    const int p = blockIdx.x * 4 + wid;      // b*S + t
    const int b = p >> 7;
    const int t = p & 127;
    const __hip_bfloat16* h =
        hs + (size_t)(t + 1) * (B_ * H_) + (size_t)b * H_;
    float s0 = 0.f, s1 = 0.f;
#pragma unroll
    for (int i = 0; i < 16; ++i) {
        int n = lane + 64 * i;
        float hv = __bfloat162float(h[n]);
        s0 += hv * lin_W[n];
        s1 += hv * lin_W[H_ + n];
    }
#pragma unroll
    for (int off = 32; off > 0; off >>= 1) {
        s0 += __shfl_down(s0, off);
        s1 += __shfl_down(s1, off);
    }
    if (lane == 0) {
        float* o = out + (size_t)p * 2;
        if (t < lengths[b]) {
            o[0] = s0 + lin_b[0];
            o[1] = s1 + lin_b[1];
        } else {
            o[0] = 1.0f;
            o[1] = 0.0f;
        }
    }
}

extern "C" void kernel_launch(void* const* d_in, const int* in_sizes, int n_in,
                              void* d_out, int out_size, void* d_ws,
                              size_t ws_size, hipStream_t stream) {
    const int* x              = (const int*)d_in[0];
    const int* lengths        = (const int*)d_in[1];
    const float* embed_W      = (const float*)d_in[2];
    const float* W_ih         = (const float*)d_in[3];
    const float* W_hh         = (const float*)d_in[4];
    const float* b_ih         = (const float*)d_in[5];
    const float* b_hh         = (const float*)d_in[6];
    const float* lin_W        = (const float*)d_in[7];
    const float* lin_b        = (const float*)d_in[8];
    float* out                = (float*)d_out;

    // ws layout (256-aligned):
    //   hs bf16 [S+1,B,H]        @ 0           (33,816,576)
    //   gates fp16 [S*B,4096]    @ 33,816,576  (134,217,728)
    //   bias fp32 [4096]         @ 168,034,304 (16,384)
    //   bar int[4*64]            @ 168,050,688 (1,024)
    char* ws = (char*)d_ws;
    __hip_bfloat16* hs  = (__hip_bfloat16*)(ws + 0);
    __half* gates       = (__half*)(ws + 33816576);
    float* bias         = (float*)(ws + 168034304);
    int* bar            = (int*)(ws + 168050688);

    prep_bias<<<16, 256, 0, stream>>>(b_ih, b_hh, bias);
    (void)hipMemsetAsync(hs, 0, (size_t)B_ * H_ * sizeof(__hip_bfloat16), stream);
    (void)hipMemsetAsync(bar, 0, 4 * 64 * sizeof(int), stream);

    gemm_ih<<<dim3(32, 128), 256, 0, stream>>>(x, embed_W, W_ih, bias, gates);

    void* kargs[] = {(void*)&W_hh, (void*)&gates, (void*)&hs, (void*)&bar};
    (void)hipLaunchCooperativeKernel((const void*)lstm_persist, dim3(256),
                                     dim3(256), kargs, 0, stream);

    final_linear<<<dim3((B_ * S_) / 4), 256, 0, stream>>>(
        hs, lin_W, lin_b, lengths, out);
}

// Round 7
// 1067.490 us; speedup vs baseline: 5.4662x; 5.4662x over previous
//
#include <hip/hip_runtime.h>
#include <hip/hip_bf16.h>
#include <hip/hip_fp16.h>

#define B_ 128
#define S_ 128
#define I_ 300
#define H_ 1024
#define C_ 2

typedef __attribute__((ext_vector_type(8))) short short8;
typedef __attribute__((ext_vector_type(4))) float f32x4;

__device__ inline short f2b(float f) {
    union { __hip_bfloat16 h; unsigned short s; } cv;
    cv.h = __float2bfloat16(f);
    return (short)cv.s;
}

__global__ __launch_bounds__(256) void prep_bias(
    const float* __restrict__ b_ih, const float* __restrict__ b_hh,
    float* __restrict__ bias)
{
    int i = blockIdx.x * 256 + threadIdx.x;
    if (i < 4 * H_) bias[i] = b_ih[i] + b_hh[i];
}

// ---------------------------------------------------------------------------
// Wfrag: W_hh re-laid out in per-lane MFMA B-fragment order, bf16.
//   flat[(((ug*4 + wid)*32 + f)*64 + lane)*8 + j]
//     = bf16( W_hh[wid*1024 + ug*16 + (lane&15)][f*32 + (lane>>4)*8 + j] )
// At step time lane loads frag f with ONE coalesced 16-B load.
// ---------------------------------------------------------------------------
__global__ __launch_bounds__(256) void prep_wfrag(
    const float* __restrict__ W_hh,        // [4096,1024] fp32
    unsigned short* __restrict__ Wfrag)    // [64*4*32*64*8] bf16
{
    int idx = blockIdx.x * 256 + threadIdx.x;   // 0 .. 524287
    const int lane = idx & 63;
    const int f    = (idx >> 6) & 31;
    const int wid  = (idx >> 11) & 3;
    const int ug   = idx >> 13;
    const int row  = wid * H_ + ug * 16 + (lane & 15);
    const int k0   = f * 32 + (lane >> 4) * 8;
    const float* src = W_hh + (size_t)row * H_ + k0;
    unsigned short* dst = Wfrag + (size_t)idx * 8;
#pragma unroll
    for (int j = 0; j < 8; ++j)
        dst[j] = (unsigned short)f2b(src[j]);
}

// ---------------------------------------------------------------------------
// gates_ih[t*B+b][4096] = embed_W[x[b,t]] @ W_ih^T + (b_ih + b_hh), fp16.
// ---------------------------------------------------------------------------
__global__ __launch_bounds__(256) void gemm_ih(
    const int* __restrict__ x,            // [B,S]
    const float* __restrict__ embed_W,    // [V,300]
    const float* __restrict__ W_ih,       // [4096,300]
    const float* __restrict__ bias,       // [4096]
    __half* __restrict__ gates)           // [S*B,4096]
{
    const int tid = threadIdx.x;
    const int wid = tid >> 6, lane = tid & 63;
    const int fr = lane & 15, fq = lane >> 4;
    const int bx = blockIdx.x;            // n-tile base bx*128
    const int t  = blockIdx.y;            // this m-tile is (t, all b)

    __shared__ alignas(16) unsigned short As_[128][40];
    __shared__ alignas(16) unsigned short Bs_[128][40];

    const int sr = tid >> 1;              // staging row 0..127
    const int sc = (tid & 1) * 16;        // staging col base (16 cols)
    const int token = x[sr * S_ + t];     // b = sr
    const float* arow = embed_W + (size_t)token * I_;
    const float* brow = W_ih + (size_t)(bx * 128 + sr) * I_;

    f32x4 acc[2][8] = {};

    for (int kc = 0; kc < 10; ++kc) {
        __syncthreads();
        const int k0 = kc * 32 + sc;
#pragma unroll
        for (int half = 0; half < 2; ++half) {
            const int kh = k0 + half * 8;
            short8 av, bv;
            if (kh + 7 < I_) {
                float4 alo = *(const float4*)(arow + kh);
                float4 ahi = *(const float4*)(arow + kh + 4);
                float4 blo = *(const float4*)(brow + kh);
                float4 bhi = *(const float4*)(brow + kh + 4);
                av[0]=f2b(alo.x); av[1]=f2b(alo.y); av[2]=f2b(alo.z); av[3]=f2b(alo.w);
                av[4]=f2b(ahi.x); av[5]=f2b(ahi.y); av[6]=f2b(ahi.z); av[7]=f2b(ahi.w);
                bv[0]=f2b(blo.x); bv[1]=f2b(blo.y); bv[2]=f2b(blo.z); bv[3]=f2b(blo.w);
                bv[4]=f2b(bhi.x); bv[5]=f2b(bhi.y); bv[6]=f2b(bhi.z); bv[7]=f2b(bhi.w);
            } else {
#pragma unroll
                for (int j = 0; j < 8; ++j) {
                    av[j] = (kh + j < I_) ? f2b(arow[kh + j]) : (short)0;
                    bv[j] = (kh + j < I_) ? f2b(brow[kh + j]) : (short)0;
                }
            }
            *(short8*)&As_[sr][sc + half * 8] = av;
            *(short8*)&Bs_[sr][sc + half * 8] = bv;
        }
        __syncthreads();
        short8 bfrag[8];
#pragma unroll
        for (int nt = 0; nt < 8; ++nt)
            bfrag[nt] = *(const short8*)&Bs_[nt * 16 + fr][fq * 8];
#pragma unroll
        for (int mt = 0; mt < 2; ++mt) {
            short8 a = *(const short8*)&As_[wid * 32 + mt * 16 + fr][fq * 8];
#pragma unroll
            for (int nt = 0; nt < 8; ++nt)
                acc[mt][nt] = __builtin_amdgcn_mfma_f32_16x16x32_bf16(
                    a, bfrag[nt], acc[mt][nt], 0, 0, 0);
        }
    }
    // epilogue: C row = fq*4+r (in-tile), col = fr
#pragma unroll
    for (int mt = 0; mt < 2; ++mt) {
        const int m = t * 128 + wid * 32 + mt * 16 + fq * 4;
#pragma unroll
        for (int nt = 0; nt < 8; ++nt) {
            const int n = bx * 128 + nt * 16 + fr;
            const float bs = bias[n];
#pragma unroll
            for (int r = 0; r < 4; ++r)
                gates[(size_t)(m + r) * 4096 + n] =
                    __float2half(acc[mt][nt][r] + bs);
        }
    }
}

// ---------------------------------------------------------------------------
// Per-timestep kernel v2: K=1024 (hh part only), W fragments loaded straight
// from pre-swizzled Wfrag to registers (32 coalesced 16-B loads/lane, no LDS
// for W, no K-loop barriers). h slab staged once to LDS. Cross-step h
// coherence is handled by the kernel dispatch boundary (runtime agent
// acquire/release) — no fences, no atomics.
//   grid (64 ug, 4 bg) = 256 blocks, 256 thr = 4 waves; wave = gate.
// ---------------------------------------------------------------------------
__global__ __launch_bounds__(256, 1) void lstm_step_v2(
    const unsigned short* __restrict__ Wfrag,   // swizzled W_hh bf16
    const __half* __restrict__ gates_ih,        // [S*B,4096] incl bias
    float* __restrict__ c_state,                // [B,H] fp32
    __hip_bfloat16* __restrict__ hs,            // [S+1,B,H]
    int t)
{
    const int tid  = threadIdx.x;
    const int wid  = tid >> 6;            // wave = gate
    const int lane = tid & 63;
    const int ug = blockIdx.x;
    const int bg = blockIdx.y;
    const int n0 = ug * 16;
    const int fr = lane & 15, fq = lane >> 4;
    const int m0g = bg * 32;              // batch base

    // row stride 1048 shorts = 2096 B (16B-aligned; start-bank step 12 ->
    // period 8 over 16 rows = 2-way only, free per m136)
    __shared__ alignas(16) unsigned short As[32][1048];  // h slab 32x1024
    __shared__ float Gs[32][65];                          // gate exchange

    // ---- W fragments: 32 coalesced 16B loads straight to registers ----
    short8 bfr[32];
    {
        const unsigned short* wf =
            Wfrag + ((size_t)((ug * 4 + wid) * 32) * 64 + lane) * 8;
#pragma unroll
        for (int f = 0; f < 32; ++f)
            bfr[f] = *(const short8*)(wf + (size_t)f * 512);
    }

    // ---- stage h_prev slab [32][1024] to LDS (plain coalesced loads) ----
    {
        const __hip_bfloat16* hprev =
            hs + (size_t)t * (B_ * H_) + (size_t)m0g * H_;
#pragma unroll
        for (int i = 0; i < 16; ++i) {
            const int e = i * 256 + tid;          // 0..4095 16B-chunks
            const int r = e >> 7, ch = (e & 127) * 8;
            *(short8*)&As[r][ch] = *(const short8*)(hprev + r * H_ + ch);
        }
    }
    __syncthreads();

    // ---- 64 MFMAs: full K=1024 ----
    f32x4 acc0 = {0.f,0.f,0.f,0.f}, acc1 = {0.f,0.f,0.f,0.f};
    {
        const unsigned short* a0p = &As[fr][fq * 8];
        const unsigned short* a1p = &As[16 + fr][fq * 8];
#pragma unroll
        for (int f = 0; f < 32; ++f) {
            short8 a0 = *(const short8*)(a0p + f * 32);
            short8 a1 = *(const short8*)(a1p + f * 32);
            acc0 = __builtin_amdgcn_mfma_f32_16x16x32_bf16(a0, bfr[f], acc0, 0, 0, 0);
            acc1 = __builtin_amdgcn_mfma_f32_16x16x32_bf16(a1, bfr[f], acc1, 0, 0, 0);
        }
    }

    // ---- exchange gates: Gs[m][gate*16+u] ----
    {
        const int col = wid * 16 + fr;
        const int rb = fq * 4;
#pragma unroll
        for (int r = 0; r < 4; ++r) {
            Gs[rb + r][col]      = acc0[r];
            Gs[16 + rb + r][col] = acc1[r];
        }
    }
    __syncthreads();

    // ---- cell update: thread owns units (u0,u0+1) of batch row m0g+cm2 ----
    {
        const int cm2 = tid >> 3, up = tid & 7;
        const int u0 = 2 * up;
        const size_t rowbase = ((size_t)t * B_ + m0g + cm2) * 4096 + n0;
        const __half2* gih = (const __half2*)(gates_ih + rowbase);
        float2 gi = __half22float2(gih[up]);
        float2 gf = __half22float2(gih[up + 512]);
        float2 gg = __half22float2(gih[up + 1024]);
        float2 go = __half22float2(gih[up + 1536]);
        float gi0 = Gs[cm2][u0]          + gi.x;
        float gi1 = Gs[cm2][u0 + 1]      + gi.y;
        float gf0 = Gs[cm2][16 + u0]     + gf.x;
        float gf1 = Gs[cm2][16 + u0 + 1] + gf.y;
        float gg0 = Gs[cm2][32 + u0]     + gg.x;
        float gg1 = Gs[cm2][32 + u0 + 1] + gg.y;
        float go0 = Gs[cm2][48 + u0]     + go.x;
        float go1 = Gs[cm2][48 + u0 + 1] + go.y;
        float si0 = 1.f / (1.f + __expf(-gi0));
        float sf0 = 1.f / (1.f + __expf(-gf0));
        float so0 = 1.f / (1.f + __expf(-go0));
        float si1 = 1.f / (1.f + __expf(-gi1));
        float sf1 = 1.f / (1.f + __expf(-gf1));
        float so1 = 1.f / (1.f + __expf(-go1));
        float* cp = c_state + (size_t)(m0g + cm2) * H_ + n0 + u0;
        float2 cc = *(float2*)cp;
        cc.x = sf0 * cc.x + si0 * tanhf(gg0);
        cc.y = sf1 * cc.y + si1 * tanhf(gg1);
        *(float2*)cp = cc;
        float h0 = so0 * tanhf(cc.x);
        float h1 = so1 * tanhf(cc.y);
        unsigned int hv =
            (unsigned int)(unsigned short)f2b(h0) |
            ((unsigned int)(unsigned short)f2b(h1) << 16);
        unsigned int* dst = (unsigned int*)
            (hs + (size_t)(t + 1) * (B_ * H_) +
             (size_t)(m0g + cm2) * H_ + n0) + up;
        *dst = hv;
    }
}

// ---------------------------------------------------------------------------
// Head: one wave per (b,t): out = h . lin_W^T + lin_b, masked by lengths.
// ---------------------------------------------------------------------------
__global__ __launch_bounds__(256) void final_linear(
    const __hip_bfloat16* __restrict__ hs,   // [S+1,B,H]
    const float* __restrict__ lin_W,         // [2,H]
    const float* __restrict__ lin_b,         // [2]
    const int* __restrict__ lengths,         // [B]
    float* __restrict__ out)                 // [B*S,2]
{
    const int wid  = threadIdx.x >> 6;
    const int lane = threadIdx.x & 63;
    const int p = blockIdx.x * 4 + wid;      // b*S + t
    const int b = p >> 7;
    const int t = p & 127;
    const __hip_bfloat16* h =
        hs + (size_t)(t + 1) * (B_ * H_) + (size_t)b * H_;
    float s0 = 0.f, s1 = 0.f;
#pragma unroll
    for (int i = 0; i < 16; ++i) {
        int n = lane + 64 * i;
        float hv = __bfloat162float(h[n]);
        s0 += hv * lin_W[n];
        s1 += hv * lin_W[H_ + n];
    }
#pragma unroll
    for (int off = 32; off > 0; off >>= 1) {
        s0 += __shfl_down(s0, off);
        s1 += __shfl_down(s1, off);
    }
    if (lane == 0) {
        float* o = out + (size_t)p * 2;
        if (t < lengths[b]) {
            o[0] = s0 + lin_b[0];
            o[1] = s1 + lin_b[1];
        } else {
            o[0] = 1.0f;
            o[1] = 0.0f;
        }
    }
}

extern "C" void kernel_launch(void* const* d_in, const int* in_sizes, int n_in,
                              void* d_out, int out_size, void* d_ws,
                              size_t ws_size, hipStream_t stream) {
    const int* x              = (const int*)d_in[0];
    const int* lengths        = (const int*)d_in[1];
    const float* embed_W      = (const float*)d_in[2];
    const float* W_ih         = (const float*)d_in[3];
    const float* W_hh         = (const float*)d_in[4];
    const float* b_ih         = (const float*)d_in[5];
    const float* b_hh         = (const float*)d_in[6];
    const float* lin_W        = (const float*)d_in[7];
    const float* lin_b        = (const float*)d_in[8];
    float* out                = (float*)d_out;

    // ws layout (256-aligned):
    //   hs bf16 [S+1,B,H]        @ 0            (33,816,576)
    //   gates fp16 [S*B,4096]    @ 33,816,576   (134,217,728)
    //   bias fp32 [4096]         @ 168,034,304  (16,384)
    //   Wfrag bf16 [4M]          @ 168,050,688  (8,388,608)
    //   c_state fp32 [B,H]       @ 176,439,296  (524,288)
    char* ws = (char*)d_ws;
    __hip_bfloat16* hs    = (__hip_bfloat16*)(ws + 0);
    __half* gates         = (__half*)(ws + 33816576);
    float* bias           = (float*)(ws + 168034304);
    unsigned short* Wfrag = (unsigned short*)(ws + 168050688);
    float* c_state        = (float*)(ws + 176439296);

    prep_bias<<<16, 256, 0, stream>>>(b_ih, b_hh, bias);
    prep_wfrag<<<2048, 256, 0, stream>>>(W_hh, Wfrag);
    (void)hipMemsetAsync(hs, 0, (size_t)B_ * H_ * sizeof(__hip_bfloat16), stream);
    (void)hipMemsetAsync(c_state, 0, (size_t)B_ * H_ * sizeof(float), stream);

    gemm_ih<<<dim3(32, 128), 256, 0, stream>>>(x, embed_W, W_ih, bias, gates);

    for (int t = 0; t < S_; ++t) {
        lstm_step_v2<<<dim3(64, 4), 256, 0, stream>>>(
            Wfrag, gates, c_state, hs, t);
    }

    final_linear<<<dim3((B_ * S_) / 4), 256, 0, stream>>>(
        hs, lin_W, lin_b, lengths, out);
}

// Round 9
// 979.291 us; speedup vs baseline: 5.9585x; 1.0901x over previous
//
#include <hip/hip_runtime.h>
#include <hip/hip_bf16.h>
#include <hip/hip_fp16.h>

#define B_ 128
#define S_ 128
#define I_ 300
#define IP_ 320
#define H_ 1024
#define C_ 2

typedef __attribute__((ext_vector_type(8))) short short8;
typedef __attribute__((ext_vector_type(4))) float f32x4;

__device__ inline short f2b(float f) {
    union { __hip_bfloat16 h; unsigned short s; } cv;
    cv.h = __float2bfloat16(f);
    return (short)cv.s;
}

__global__ __launch_bounds__(256) void prep_bias(
    const float* __restrict__ b_ih, const float* __restrict__ b_hh,
    float* __restrict__ bias)
{
    int i = blockIdx.x * 256 + threadIdx.x;
    if (i < 4 * H_) bias[i] = b_ih[i] + b_hh[i];
}

// W_ihp bf16 [4096][320], zero-padded cols 300..319
__global__ __launch_bounds__(256) void prep_wih(
    const float* __restrict__ W_ih, unsigned short* __restrict__ Wp)
{
    int idx = blockIdx.x * 256 + threadIdx.x;
    if (idx >= 4096 * IP_) return;
    int row = idx / IP_, k = idx - row * IP_;
    Wp[idx] = (k < I_) ? (unsigned short)f2b(W_ih[row * I_ + k]) : 0;
}

// xe bf16 [S][B][320]: gathered embedding rows, zero-padded
__global__ __launch_bounds__(256) void prep_xe(
    const int* __restrict__ x, const float* __restrict__ embed_W,
    unsigned short* __restrict__ xe)
{
    int idx = blockIdx.x * 256 + threadIdx.x;
    if (idx >= S_ * B_ * IP_) return;
    int k = idx % IP_;
    int tb = idx / IP_;
    int b = tb % B_, t = tb / B_;
    int row = x[b * S_ + t];
    xe[idx] = (k < I_) ? (unsigned short)f2b(embed_W[(size_t)row * I_ + k]) : 0;
}

// Wfrag: W_hh in per-lane MFMA B-fragment order (R6/R7-proven layout)
__global__ __launch_bounds__(256) void prep_wfrag(
    const float* __restrict__ W_hh, unsigned short* __restrict__ Wfrag)
{
    int idx = blockIdx.x * 256 + threadIdx.x;   // 0 .. 524287
    const int lane = idx & 63;
    const int f    = (idx >> 6) & 31;
    const int wid  = (idx >> 11) & 3;
    const int ug   = idx >> 13;
    const int row  = wid * H_ + ug * 16 + (lane & 15);
    const int k0   = f * 32 + (lane >> 4) * 8;
    const float* src = W_hh + (size_t)row * H_ + k0;
    unsigned short* dst = Wfrag + (size_t)idx * 8;
#pragma unroll
    for (int j = 0; j < 8; ++j)
        dst[j] = (unsigned short)f2b(src[j]);
}

// ---------------------------------------------------------------------------
// gates in FRAGMENT layout (half bits):
//   idx = t*524288 + bx*16384 + nt*2048 + fr*128 + fq*32 + wp*8 + mt*4 + r
//   holds gate for col n = bx*128+nt*16+fr, batch m = wp*32+mt*16+fq*4+r.
// Producer stores one coalesced 16-B short8 per nt (mt 0,1 packed);
// consumer (step kernel, wave=gate wid, block ug,bg) reads its 8 values
// with ONE 16-B load: bx = wid*8+(ug>>3), nt = ug&7, wp = bg.
// ---------------------------------------------------------------------------
__global__ __launch_bounds__(256) void gemm_ih(
    const unsigned short* __restrict__ xe,   // [S][B][320] bf16
    const unsigned short* __restrict__ Wp,   // [4096][320] bf16
    const float* __restrict__ bias,          // [4096]
    unsigned short* __restrict__ gates)      // frag layout, half bits
{
    const int tid = threadIdx.x;
    const int wid = tid >> 6, lane = tid & 63;
    const int fr = lane & 15, fq = lane >> 4;
    const int bx = blockIdx.x;            // n-tile base bx*128
    const int t  = blockIdx.y;

    __shared__ alignas(16) unsigned short As_[128][40];
    __shared__ alignas(16) unsigned short Bs_[128][40];

    const int sr = tid >> 1;
    const int sc = (tid & 1) * 16;
    const unsigned short* arow = xe + ((size_t)t * B_ + sr) * IP_;
    const unsigned short* brow = Wp + (size_t)(bx * 128 + sr) * IP_;

    f32x4 acc[2][8] = {};

    for (int kc = 0; kc < 10; ++kc) {
        __syncthreads();
        const int k0 = kc * 32 + sc;
        *(short8*)&As_[sr][sc]     = *(const short8*)(arow + k0);
        *(short8*)&As_[sr][sc + 8] = *(const short8*)(arow + k0 + 8);
        *(short8*)&Bs_[sr][sc]     = *(const short8*)(brow + k0);
        *(short8*)&Bs_[sr][sc + 8] = *(const short8*)(brow + k0 + 8);
        __syncthreads();
        short8 bfrag[8];
#pragma unroll
        for (int nt = 0; nt < 8; ++nt)
            bfrag[nt] = *(const short8*)&Bs_[nt * 16 + fr][fq * 8];
#pragma unroll
        for (int mt = 0; mt < 2; ++mt) {
            short8 a = *(const short8*)&As_[wid * 32 + mt * 16 + fr][fq * 8];
#pragma unroll
            for (int nt = 0; nt < 8; ++nt)
                acc[mt][nt] = __builtin_amdgcn_mfma_f32_16x16x32_bf16(
                    a, bfrag[nt], acc[mt][nt], 0, 0, 0);
        }
    }
    // epilogue: one coalesced 16-B store per nt
    unsigned short* gbase = gates + (size_t)t * 524288 + (size_t)bx * 16384
                          + fr * 128 + fq * 32 + wid * 8;
#pragma unroll
    for (int nt = 0; nt < 8; ++nt) {
        const float bs = bias[bx * 128 + nt * 16 + fr];
        short8 pk;
#pragma unroll
        for (int r = 0; r < 4; ++r) {
            pk[r]     = (short)__half_as_ushort(__float2half(acc[0][nt][r] + bs));
            pk[4 + r] = (short)__half_as_ushort(__float2half(acc[1][nt][r] + bs));
        }
        *(short8*)(gbase + nt * 2048) = pk;
    }
}

// ---------------------------------------------------------------------------
// Per-timestep kernel v3 (R7-proven structure + fused frag-layout gates):
// K=1024, W fragments straight from pre-swizzled Wfrag to registers; h slab
// staged once to LDS; cross-step coherence via kernel dispatch boundary.
// grid (64 ug, 4 bg) = 256 blocks, 256 thr = 4 waves; wave = gate.
// ---------------------------------------------------------------------------
__global__ __launch_bounds__(256, 1) void lstm_step_v3(
    const unsigned short* __restrict__ Wfrag,
    const unsigned short* __restrict__ gates,   // frag layout, half bits
    float* __restrict__ c_state,                // [B,H] fp32
    __hip_bfloat16* __restrict__ hs,            // [S+1,B,H]
    int t)
{
    const int tid  = threadIdx.x;
    const int wid  = tid >> 6;            // wave = gate
    const int lane = tid & 63;
    const int ug = blockIdx.x;
    const int bg = blockIdx.y;
    const int n0 = ug * 16;
    const int fr = lane & 15, fq = lane >> 4;
    const int m0g = bg * 32;

    __shared__ alignas(16) unsigned short As[32][1048];  // h slab 32x1024
    __shared__ float Gs[32][65];                          // gate exchange

    // ---- W fragments: 32 coalesced 16B loads straight to registers ----
    short8 bfr[32];
    {
        const unsigned short* wf =
            Wfrag + ((size_t)((ug * 4 + wid) * 32) * 64 + lane) * 8;
#pragma unroll
        for (int f = 0; f < 32; ++f)
            bfr[f] = *(const short8*)(wf + (size_t)f * 512);
    }

    // ---- fused ih-gates: ONE coalesced 16-B load per lane ----
    union { short8 v; __half h[8]; } gih;
    {
        const unsigned short* gp = gates + (size_t)t * 524288
            + (size_t)(wid * 8 + (ug >> 3)) * 16384
            + (size_t)(ug & 7) * 2048 + fr * 128 + fq * 32 + bg * 8;
        gih.v = *(const short8*)gp;
    }

    // ---- stage h_prev slab [32][1024] to LDS ----
    {
        const __hip_bfloat16* hprev =
            hs + (size_t)t * (B_ * H_) + (size_t)m0g * H_;
#pragma unroll
        for (int i = 0; i < 16; ++i) {
            const int e = i * 256 + tid;          // 16B-chunk id
            const int r = e >> 7, ch = (e & 127) * 8;
            *(short8*)&As[r][ch] = *(const short8*)(hprev + r * H_ + ch);
        }
    }
    __syncthreads();

    // ---- 64 MFMAs: full K=1024 ----
    f32x4 acc0 = {0.f,0.f,0.f,0.f}, acc1 = {0.f,0.f,0.f,0.f};
    {
        const unsigned short* a0p = &As[fr][fq * 8];
        const unsigned short* a1p = &As[16 + fr][fq * 8];
#pragma unroll
        for (int f = 0; f < 32; ++f) {
            short8 a0 = *(const short8*)(a0p + f * 32);
            short8 a1 = *(const short8*)(a1p + f * 32);
            acc0 = __builtin_amdgcn_mfma_f32_16x16x32_bf16(a0, bfr[f], acc0, 0, 0, 0);
            acc1 = __builtin_amdgcn_mfma_f32_16x16x32_bf16(a1, bfr[f], acc1, 0, 0, 0);
        }
    }

    // fused add of precomputed ih-gates (+bias), before the exchange
#pragma unroll
    for (int r = 0; r < 4; ++r) {
        acc0[r] += __half2float(gih.h[r]);
        acc1[r] += __half2float(gih.h[4 + r]);
    }

    // ---- exchange complete gates: Gs[m][gate*16+u] ----
    {
        const int col = wid * 16 + fr;
        const int rb = fq * 4;
#pragma unroll
        for (int r = 0; r < 4; ++r) {
            Gs[rb + r][col]      = acc0[r];
            Gs[16 + rb + r][col] = acc1[r];
        }
    }
    __syncthreads();

    // ---- cell update: thread owns units (u0,u0+1) of batch row m0g+cm2 ----
    {
        const int cm2 = tid >> 3, up = tid & 7;
        const int u0 = 2 * up;
        float gi0 = Gs[cm2][u0],      gi1 = Gs[cm2][u0 + 1];
        float gf0 = Gs[cm2][16 + u0], gf1 = Gs[cm2][16 + u0 + 1];
        float gg0 = Gs[cm2][32 + u0], gg1 = Gs[cm2][32 + u0 + 1];
        float go0 = Gs[cm2][48 + u0], go1 = Gs[cm2][48 + u0 + 1];
        float si0 = 1.f / (1.f + __expf(-gi0));
        float sf0 = 1.f / (1.f + __expf(-gf0));
        float so0 = 1.f / (1.f + __expf(-go0));
        float si1 = 1.f / (1.f + __expf(-gi1));
        float sf1 = 1.f / (1.f + __expf(-gf1));
        float so1 = 1.f / (1.f + __expf(-go1));
        float* cp = c_state + (size_t)(m0g + cm2) * H_ + n0 + u0;
        float2 cc = *(float2*)cp;
        cc.x = sf0 * cc.x + si0 * tanhf(gg0);
        cc.y = sf1 * cc.y + si1 * tanhf(gg1);
        *(float2*)cp = cc;
        float h0 = so0 * tanhf(cc.x);
        float h1 = so1 * tanhf(cc.y);
        unsigned int hv =
            (unsigned int)(unsigned short)f2b(h0) |
            ((unsigned int)(unsigned short)f2b(h1) << 16);
        unsigned int* dst = (unsigned int*)
            (hs + (size_t)(t + 1) * (B_ * H_) +
             (size_t)(m0g + cm2) * H_ + n0) + up;
        *dst = hv;
    }
}

// ---------------------------------------------------------------------------
// Head: one wave per (b,t): out = h . lin_W^T + lin_b, masked by lengths.
// ---------------------------------------------------------------------------
__global__ __launch_bounds__(256) void final_linear(
    const __hip_bfloat16* __restrict__ hs,
    const float* __restrict__ lin_W,
    const float* __restrict__ lin_b,
    const int* __restrict__ lengths,
    float* __restrict__ out)
{
    const int wid  = threadIdx.x >> 6;
    const int lane = threadIdx.x & 63;
    const int p = blockIdx.x * 4 + wid;
    const int b = p >> 7;
    const int t = p & 127;
    const __hip_bfloat16* h =
        hs + (size_t)(t + 1) * (B_ * H_) + (size_t)b * H_;
    float s0 = 0.f, s1 = 0.f;
#pragma unroll
    for (int i = 0; i < 16; ++i) {
        int n = lane + 64 * i;
        float hv = __bfloat162float(h[n]);
        s0 += hv * lin_W[n];
        s1 += hv * lin_W[H_ + n];
    }
#pragma unroll
    for (int off = 32; off > 0; off >>= 1) {
        s0 += __shfl_down(s0, off);
        s1 += __shfl_down(s1, off);
    }
    if (lane == 0) {
        float* o = out + (size_t)p * 2;
        if (t < lengths[b]) {
            o[0] = s0 + lin_b[0];
            o[1] = s1 + lin_b[1];
        } else {
            o[0] = 1.0f;
            o[1] = 0.0f;
        }
    }
}

extern "C" void kernel_launch(void* const* d_in, const int* in_sizes, int n_in,
                              void* d_out, int out_size, void* d_ws,
                              size_t ws_size, hipStream_t stream) {
    const int* x              = (const int*)d_in[0];
    const int* lengths        = (const int*)d_in[1];
    const float* embed_W      = (const float*)d_in[2];
    const float* W_ih         = (const float*)d_in[3];
    const float* W_hh         = (const float*)d_in[4];
    const float* b_ih         = (const float*)d_in[5];
    const float* b_hh         = (const float*)d_in[6];
    const float* lin_W        = (const float*)d_in[7];
    const float* lin_b        = (const float*)d_in[8];
    float* out                = (float*)d_out;

    // ws layout (R7 footprint, 176,963,584 B total):
    //   hs bf16 [S+1,B,H]      @ 0            (33,816,576)
    //   gates half (frag)      @ 33,816,576   (134,217,728)
    //   bias fp32 [4096]       @ 168,034,304  (16,384)
    //   Wfrag bf16             @ 168,050,688  (8,388,608)
    //   c_state fp32 [B,H]     @ 176,439,296  (524,288)
    //   xe bf16 [S,B,320]      @ hs+262,144   (10,485,760) [alias, consumed
    //   W_ihp bf16 [4096,320]  @ hs+10,747,904 (2,621,440)  before steps]
    char* ws = (char*)d_ws;
    __hip_bfloat16* hs    = (__hip_bfloat16*)(ws + 0);
    unsigned short* gates = (unsigned short*)(ws + 33816576);
    float* bias           = (float*)(ws + 168034304);
    unsigned short* Wfrag = (unsigned short*)(ws + 168050688);
    float* c_state        = (float*)(ws + 176439296);
    unsigned short* xe    = (unsigned short*)(ws + 262144);
    unsigned short* Wp    = (unsigned short*)(ws + 10747904);

    prep_bias<<<16, 256, 0, stream>>>(b_ih, b_hh, bias);
    prep_wih<<<(4096 * IP_ + 255) / 256, 256, 0, stream>>>(W_ih, Wp);
    prep_xe<<<(S_ * B_ * IP_ + 255) / 256, 256, 0, stream>>>(x, embed_W, xe);
    prep_wfrag<<<2048, 256, 0, stream>>>(W_hh, Wfrag);
    (void)hipMemsetAsync(hs, 0, (size_t)B_ * H_ * sizeof(__hip_bfloat16), stream);
    (void)hipMemsetAsync(c_state, 0, (size_t)B_ * H_ * sizeof(float), stream);

    gemm_ih<<<dim3(32, 128), 256, 0, stream>>>(xe, Wp, bias, gates);

    for (int t = 0; t < S_; ++t) {
        lstm_step_v3<<<dim3(64, 4), 256, 0, stream>>>(
            Wfrag, gates, c_state, hs, t);
    }

    final_linear<<<dim3((B_ * S_) / 4), 256, 0, stream>>>(
        hs, lin_W, lin_b, lengths, out);
}